// Round 1
// baseline (206.967 us; speedup 1.0000x reference)
//
#include <hip/hip_runtime.h>
#include <hip/hip_bf16.h>
#include <cstdint>
#include <cstddef>

// Problem dims
#define NB 2
#define NL 2048
#define NE 1024
#define NH 16
#define ND 64
#define NM (NB * NL)  // 4096 rows total

typedef float f32x4 __attribute__((ext_vector_type(4)));
typedef __bf16 bf16x8 __attribute__((ext_vector_type(8)));

#define DEV static __device__ __forceinline__

DEV f32x4 mfma16(bf16x8 a, bf16x8 b, f32x4 c) {
  return __builtin_amdgcn_mfma_f32_16x16x32_bf16(a, b, c, 0, 0, 0);
}

DEV ushort f2bf(float f) {
  uint32_t u = __float_as_uint(f);
  uint32_t r = (u + 0x7fffu + ((u >> 16) & 1u)) >> 16;
  return (ushort)r;
}

DEV void gl_lds16(const void* src, void* lds_dst) {
  __builtin_amdgcn_global_load_lds(
      (const __attribute__((address_space(1))) void*)src,
      (__attribute__((address_space(3))) void*)lds_dst, 16, 0, 0);
}

// Stage a tile whose rows are 128 bytes (64 bf16) into LDS, linear dest,
// source pre-swizzled with the involution byte ^= ((row&7)<<4) so that
// swizzled ds_read_b128 fragment reads are bank-conflict-reduced.
template <int NCALLS>
DEV void stage_swz(const char* gbase, size_t row_stride_b, char* lds_base, int tid) {
#pragma unroll
  for (int c = 0; c < NCALLS; ++c) {
    uint32_t P = (uint32_t)(c * 4096 + tid * 16);
    uint32_t r = P >> 7;
    uint32_t Lo = P ^ ((r & 7u) << 4);
    gl_lds16(gbase + (size_t)r * row_stride_b + (Lo & 127u), lds_base + P);
  }
}

// ---------------------------------------------------------------- pack
__global__ __launch_bounds__(256) void pack_kernel(
    const float* __restrict__ x, const float* __restrict__ wq,
    const float* __restrict__ wk, const float* __restrict__ wv,
    const float* __restrict__ wo, ushort* __restrict__ xb,
    ushort* __restrict__ wqb, ushort* __restrict__ wkb,
    ushort* __restrict__ wvb, ushort* __restrict__ wob) {
  int64_t q = (int64_t)blockIdx.x * 256 + threadIdx.x;  // quad id, 2097152 total
  const float* src;
  ushort* dst;
  bool cl;
  if (q < 1048576) {
    src = x + q * 4;
    dst = xb + q * 4;
    cl = true;
  } else {
    int64_t r = q - 1048576;
    int wsel = (int)(r >> 18);
    int64_t o = (r & 262143) * 4;
    cl = false;
    if (wsel == 0) { src = wq + o; dst = wqb + o; }
    else if (wsel == 1) { src = wk + o; dst = wkb + o; }
    else if (wsel == 2) { src = wv + o; dst = wvb + o; }
    else { src = wo + o; dst = wob + o; }
  }
  float4 v = *(const float4*)src;
  if (cl) {
    v.x = (v.x != v.x) ? 0.f : fminf(fmaxf(v.x, -1e9f), 1e9f);
    v.y = (v.y != v.y) ? 0.f : fminf(fmaxf(v.y, -1e9f), 1e9f);
    v.z = (v.z != v.z) ? 0.f : fminf(fmaxf(v.z, -1e9f), 1e9f);
    v.w = (v.w != v.w) ? 0.f : fminf(fmaxf(v.w, -1e9f), 1e9f);
  }
  ushort4 o4;
  o4.x = f2bf(v.x);
  o4.y = f2bf(v.y);
  o4.z = f2bf(v.z);
  o4.w = f2bf(v.w);
  *(ushort4*)dst = o4;
}

// ---------------------------------------------------------------- QKV GEMM
// C(4096 x 3072) = xb(4096x1024) @ W^T, scattered epilogue:
//  Q,K -> (B,H,L,D) bf16 ; V -> Vt (B,H,D,L) bf16
__global__ __launch_bounds__(256) void qkv_gemm_kernel(
    const ushort* __restrict__ xb, const ushort* __restrict__ wqb,
    const ushort* __restrict__ wkb, const ushort* __restrict__ wvb,
    const float* __restrict__ bq, const float* __restrict__ bk,
    const float* __restrict__ bv, ushort* __restrict__ Qo,
    ushort* __restrict__ Ko, ushort* __restrict__ Vto) {
  __shared__ __align__(128) char lds[32768];
  const int tid = threadIdx.x;
  const int w = tid >> 6, ln = tid & 63;
  const int ln15 = ln & 15, g = ln >> 4;
  const int wm = w >> 1, wn = w & 1;
  const int m0 = blockIdx.y * 128;
  const int which = blockIdx.x >> 3;          // 0=Q 1=K 2=V
  const int n0w = (blockIdx.x & 7) * 128;     // within [0,1024)
  const ushort* Wb = (which == 0) ? wqb : (which == 1) ? wkb : wvb;

  const char* Abase = (const char*)xb + (size_t)m0 * 2048;
  const char* Bbase = (const char*)Wb + (size_t)n0w * 2048;

  f32x4 acc[4][4];
#pragma unroll
  for (int m = 0; m < 4; ++m)
#pragma unroll
    for (int n = 0; n < 4; ++n) acc[m][n] = {0.f, 0.f, 0.f, 0.f};

  for (int kt = 0; kt < 1024; kt += 64) {
    __syncthreads();
    stage_swz<4>(Abase + kt * 2, 2048, lds, tid);
    stage_swz<4>(Bbase + kt * 2, 2048, lds + 16384, tid);
    asm volatile("s_waitcnt vmcnt(0)" ::: "memory");
    __syncthreads();
#pragma unroll
    for (int kc = 0; kc < 2; ++kc) {
      bf16x8 af[4], bfr[4];
#pragma unroll
      for (int i = 0; i < 4; ++i) {
        uint32_t ar = (uint32_t)(wm * 64 + i * 16 + ln15);
        uint32_t ao = (ar * 128u + (uint32_t)(kc * 64 + g * 16)) ^ ((ar & 7u) << 4);
        af[i] = *(const bf16x8*)(lds + ao);
        uint32_t br = (uint32_t)(wn * 64 + i * 16 + ln15);
        uint32_t bo_ = 16384u + ((br * 128u + (uint32_t)(kc * 64 + g * 16)) ^ ((br & 7u) << 4));
        bfr[i] = *(const bf16x8*)(lds + bo_);
      }
#pragma unroll
      for (int m = 0; m < 4; ++m)
#pragma unroll
        for (int n = 0; n < 4; ++n) acc[m][n] = mfma16(af[m], bfr[n], acc[m][n]);
    }
  }

  const float* bias = (which == 0) ? bq : (which == 1) ? bk : bv;
#pragma unroll
  for (int n = 0; n < 4; ++n) {
    const int col = n0w + wn * 64 + n * 16 + ln15;  // [0,1024)
    const int h = col >> 6, d = col & 63;
    const float bc = bias[col];
#pragma unroll
    for (int m = 0; m < 4; ++m) {
      if (which < 2) {
        ushort* dst = (which == 0) ? Qo : Ko;
#pragma unroll
        for (int j = 0; j < 4; ++j) {
          int mg = m0 + wm * 64 + m * 16 + g * 4 + j;
          int b = mg >> 11, l = mg & 2047;
          dst[((size_t)(b * NH + h) * NL + l) * ND + d] = f2bf(acc[m][n][j] + bc);
        }
      } else {
        int mg0 = m0 + wm * 64 + m * 16 + g * 4;
        int b = mg0 >> 11, l0 = mg0 & 2047;
        ushort4 pk;
        pk.x = f2bf(acc[m][n][0] + bc);
        pk.y = f2bf(acc[m][n][1] + bc);
        pk.z = f2bf(acc[m][n][2] + bc);
        pk.w = f2bf(acc[m][n][3] + bc);
        *(ushort4*)(Vto + ((size_t)(b * NH + h) * ND + d) * NL + l0) = pk;
      }
    }
  }
}

// ---------------------------------------------------------------- attention
// Per block: one (b,h), 128 Q rows. KV tiles of 64. Online softmax.
__global__ __launch_bounds__(256) void attn_kernel(
    const ushort* __restrict__ Q, const ushort* __restrict__ K,
    const ushort* __restrict__ Vt, ushort* __restrict__ Op) {
  __shared__ __align__(128) char lds[32768];  // K 8K | Vt 8K | P 4x4K
  const int tid = threadIdx.x;
  const int w = tid >> 6, ln = tid & 63;
  const int ln15 = ln & 15, g = ln >> 4;
  const int qt = blockIdx.x, bh = blockIdx.y;
  const int b = bh >> 4, h = bh & 15;
  const ushort* Qh = Q + (size_t)bh * NL * ND;
  const ushort* Kh = K + (size_t)bh * NL * ND;
  const ushort* Vth = Vt + (size_t)bh * ND * NL;
  const int q0w = qt * 128 + w * 32;

  bf16x8 qf[2][2];
#pragma unroll
  for (int m = 0; m < 2; ++m)
#pragma unroll
    for (int kc = 0; kc < 2; ++kc)
      qf[m][kc] = *(const bf16x8*)(Qh + (size_t)(q0w + m * 16 + ln15) * ND + kc * 32 + g * 8);

  f32x4 o_acc[2][4];
  float m_run[2][4], l_run[2][4];
#pragma unroll
  for (int m = 0; m < 2; ++m)
#pragma unroll
    for (int n = 0; n < 4; ++n) o_acc[m][n] = {0.f, 0.f, 0.f, 0.f};
#pragma unroll
  for (int m = 0; m < 2; ++m)
#pragma unroll
    for (int j = 0; j < 4; ++j) {
      m_run[m][j] = -1e30f;
      l_run[m][j] = 0.f;
    }

  const int q_max_w = q0w + 31;
  const int s_end = qt * 128 + 128;
  const uint32_t pbase = 16384u + (uint32_t)w * 4096u;

  for (int s0 = 0; s0 < s_end; s0 += 64) {
    __syncthreads();
    stage_swz<2>((const char*)Kh + (size_t)s0 * 128, 128, lds, tid);
    stage_swz<2>((const char*)Vth + (size_t)s0 * 2, (size_t)NL * 2, lds + 8192, tid);
    asm volatile("s_waitcnt vmcnt(0)" ::: "memory");
    __syncthreads();
    if (s0 > q_max_w) continue;  // wave-uniform; barriers stay aligned (loop top)

    // S = Q K^T  (per wave: 32 q-rows x 64 s-cols)
    f32x4 s_acc[2][4];
#pragma unroll
    for (int m = 0; m < 2; ++m)
#pragma unroll
      for (int n = 0; n < 4; ++n) s_acc[m][n] = {0.f, 0.f, 0.f, 0.f};
#pragma unroll
    for (int kc = 0; kc < 2; ++kc) {
      bf16x8 kf[4];
#pragma unroll
      for (int n = 0; n < 4; ++n) {
        uint32_t kr = (uint32_t)(n * 16 + ln15);
        uint32_t off = (kr * 128u + (uint32_t)(kc * 64 + g * 16)) ^ ((kr & 7u) << 4);
        kf[n] = *(const bf16x8*)(lds + off);
      }
#pragma unroll
      for (int m = 0; m < 2; ++m)
#pragma unroll
        for (int n = 0; n < 4; ++n) s_acc[m][n] = mfma16(qf[m][kc], kf[n], s_acc[m][n]);
    }

    // scale + causal mask + online softmax; write P (bf16) to wave-private LDS
#pragma unroll
    for (int m = 0; m < 2; ++m) {
      float mx[4] = {-1e30f, -1e30f, -1e30f, -1e30f};
#pragma unroll
      for (int n = 0; n < 4; ++n)
#pragma unroll
        for (int j = 0; j < 4; ++j) {
          int qi = q0w + m * 16 + g * 4 + j;
          int si = s0 + n * 16 + ln15;
          float v = s_acc[m][n][j] * 0.125f;
          v = (si > qi) ? -1e30f : v;
          s_acc[m][n][j] = v;
          mx[j] = fmaxf(mx[j], v);
        }
#pragma unroll
      for (int j = 0; j < 4; ++j) {
#pragma unroll
        for (int dd = 1; dd < 16; dd <<= 1) mx[j] = fmaxf(mx[j], __shfl_xor(mx[j], dd));
        float mn = fmaxf(m_run[m][j], mx[j]);
        float al = __expf(m_run[m][j] - mn);
        m_run[m][j] = mn;
        l_run[m][j] *= al;
#pragma unroll
        for (int n = 0; n < 4; ++n) o_acc[m][n][j] *= al;
      }
      float ps[4] = {0.f, 0.f, 0.f, 0.f};
#pragma unroll
      for (int n = 0; n < 4; ++n)
#pragma unroll
        for (int j = 0; j < 4; ++j) {
          float p = __expf(s_acc[m][n][j] - m_run[m][j]);
          ps[j] += p;
          uint32_t prow = (uint32_t)(m * 16 + g * 4 + j);
          uint32_t off = (prow * 128u + (uint32_t)((n * 16 + ln15) * 2)) ^ ((prow & 7u) << 4);
          *(ushort*)(lds + pbase + off) = f2bf(p);
        }
#pragma unroll
      for (int j = 0; j < 4; ++j) {
#pragma unroll
        for (int dd = 1; dd < 16; dd <<= 1) ps[j] += __shfl_xor(ps[j], dd);
        l_run[m][j] += ps[j];
      }
    }

    // O += P V   (A-frags from P LDS, B-frags from Vt LDS)
#pragma unroll
    for (int kc = 0; kc < 2; ++kc) {
      bf16x8 pf[2], vf[4];
#pragma unroll
      for (int m = 0; m < 2; ++m) {
        uint32_t pr = (uint32_t)(m * 16 + ln15);
        uint32_t off = (pr * 128u + (uint32_t)(kc * 64 + g * 16)) ^ ((pr & 7u) << 4);
        pf[m] = *(const bf16x8*)(lds + pbase + off);
      }
#pragma unroll
      for (int n = 0; n < 4; ++n) {
        uint32_t vr = (uint32_t)(n * 16 + ln15);
        uint32_t off = (vr * 128u + (uint32_t)(kc * 64 + g * 16)) ^ ((vr & 7u) << 4);
        vf[n] = *(const bf16x8*)(lds + 8192 + off);
      }
#pragma unroll
      for (int m = 0; m < 2; ++m)
#pragma unroll
        for (int n = 0; n < 4; ++n) o_acc[m][n] = mfma16(pf[m], vf[n], o_acc[m][n]);
    }
  }

  // write O (bf16) back packed as (B*L, E)
#pragma unroll
  for (int m = 0; m < 2; ++m)
#pragma unroll
    for (int j = 0; j < 4; ++j) {
      float inv = 1.0f / l_run[m][j];
      int qi = q0w + m * 16 + g * 4 + j;
      size_t rowo = ((size_t)b * NL + qi) * NE + h * ND;
#pragma unroll
      for (int n = 0; n < 4; ++n) Op[rowo + n * 16 + ln15] = f2bf(o_acc[m][n][j] * inv);
    }
}

// ---------------------------------------------------------------- out-proj + residual
__global__ __launch_bounds__(256) void oproj_kernel(
    const ushort* __restrict__ ob, const ushort* __restrict__ wob,
    const float* __restrict__ bo, const float* __restrict__ x,
    float* __restrict__ out) {
  __shared__ __align__(128) char lds[32768];
  const int tid = threadIdx.x;
  const int w = tid >> 6, ln = tid & 63;
  const int ln15 = ln & 15, g = ln >> 4;
  const int wm = w >> 1, wn = w & 1;
  const int m0 = blockIdx.y * 128;
  const int n0 = blockIdx.x * 128;

  const char* Abase = (const char*)ob + (size_t)m0 * 2048;
  const char* Bbase = (const char*)wob + (size_t)n0 * 2048;

  f32x4 acc[4][4];
#pragma unroll
  for (int m = 0; m < 4; ++m)
#pragma unroll
    for (int n = 0; n < 4; ++n) acc[m][n] = {0.f, 0.f, 0.f, 0.f};

  for (int kt = 0; kt < 1024; kt += 64) {
    __syncthreads();
    stage_swz<4>(Abase + kt * 2, 2048, lds, tid);
    stage_swz<4>(Bbase + kt * 2, 2048, lds + 16384, tid);
    asm volatile("s_waitcnt vmcnt(0)" ::: "memory");
    __syncthreads();
#pragma unroll
    for (int kc = 0; kc < 2; ++kc) {
      bf16x8 af[4], bfr[4];
#pragma unroll
      for (int i = 0; i < 4; ++i) {
        uint32_t ar = (uint32_t)(wm * 64 + i * 16 + ln15);
        uint32_t ao = (ar * 128u + (uint32_t)(kc * 64 + g * 16)) ^ ((ar & 7u) << 4);
        af[i] = *(const bf16x8*)(lds + ao);
        uint32_t br = (uint32_t)(wn * 64 + i * 16 + ln15);
        uint32_t bo_ = 16384u + ((br * 128u + (uint32_t)(kc * 64 + g * 16)) ^ ((br & 7u) << 4));
        bfr[i] = *(const bf16x8*)(lds + bo_);
      }
#pragma unroll
      for (int m = 0; m < 4; ++m)
#pragma unroll
        for (int n = 0; n < 4; ++n) acc[m][n] = mfma16(af[m], bfr[n], acc[m][n]);
    }
  }

#pragma unroll
  for (int n = 0; n < 4; ++n) {
    const int col = n0 + wn * 64 + n * 16 + ln15;
    const float bc = bo[col];
#pragma unroll
    for (int m = 0; m < 4; ++m)
#pragma unroll
      for (int j = 0; j < 4; ++j) {
        int mg = m0 + wm * 64 + m * 16 + g * 4 + j;
        size_t idx = (size_t)mg * NE + col;
        out[idx] = acc[m][n][j] + bc + x[idx];
      }
  }
}

// ---------------------------------------------------------------- LayerNorm (in-place)
__global__ __launch_bounds__(256) void ln_kernel(float* __restrict__ io,
                                                 const float* __restrict__ gamma,
                                                 const float* __restrict__ beta) {
  const int row = blockIdx.x, tid = threadIdx.x;
  const int w = tid >> 6, ln = tid & 63;
  float4 v = *(const float4*)(io + (size_t)row * NE + tid * 4);
  float s = v.x + v.y + v.z + v.w;
  float ss = v.x * v.x + v.y * v.y + v.z * v.z + v.w * v.w;
#pragma unroll
  for (int d = 1; d < 64; d <<= 1) {
    s += __shfl_xor(s, d);
    ss += __shfl_xor(ss, d);
  }
  __shared__ float red[8];
  if (ln == 0) {
    red[w] = s;
    red[4 + w] = ss;
  }
  __syncthreads();
  s = red[0] + red[1] + red[2] + red[3];
  ss = red[4] + red[5] + red[6] + red[7];
  const float mu = s * (1.0f / (float)NE);
  float var = ss * (1.0f / (float)NE) - mu * mu;
  const float inv = rsqrtf(var + 1e-5f);
  float4 gv = *(const float4*)(gamma + tid * 4);
  float4 bv = *(const float4*)(beta + tid * 4);
  float4 o;
  o.x = (v.x - mu) * inv * gv.x + bv.x;
  o.y = (v.y - mu) * inv * gv.y + bv.y;
  o.z = (v.z - mu) * inv * gv.z + bv.z;
  o.w = (v.w - mu) * inv * gv.w + bv.w;
  *(float4*)(io + (size_t)row * NE + tid * 4) = o;
}

// ---------------------------------------------------------------- launch
extern "C" void kernel_launch(void* const* d_in, const int* in_sizes, int n_in,
                              void* d_out, int out_size, void* d_ws, size_t ws_size,
                              hipStream_t stream) {
  const float* x = (const float*)d_in[0];
  // d_in[1] = mask (causal, recomputed analytically -> unused)
  const float* Wq = (const float*)d_in[2];
  const float* bq = (const float*)d_in[3];
  const float* Wk = (const float*)d_in[4];
  const float* bk = (const float*)d_in[5];
  const float* Wv = (const float*)d_in[6];
  const float* bv = (const float*)d_in[7];
  const float* Wo = (const float*)d_in[8];
  const float* bo = (const float*)d_in[9];
  const float* gamma = (const float*)d_in[10];
  const float* beta = (const float*)d_in[11];

  char* ws = (char*)d_ws;
  ushort* xb  = (ushort*)(ws + 0);          // 8 MB  (4096x1024 bf16)
  ushort* wqb = (ushort*)(ws + 8388608);    // 2 MB
  ushort* wkb = (ushort*)(ws + 10485760);   // 2 MB
  ushort* wvb = (ushort*)(ws + 12582912);   // 2 MB
  ushort* wob = (ushort*)(ws + 14680064);   // 2 MB
  ushort* Qb  = (ushort*)(ws + 16777216);   // 8 MB (B,H,L,D)
  ushort* Kb  = (ushort*)(ws + 25165824);   // 8 MB (B,H,L,D)
  ushort* Vtb = (ushort*)(ws + 33554432);   // 8 MB (B,H,D,L)
  ushort* Ob  = (ushort*)(ws + 41943040);   // 8 MB (B*L, E)

  pack_kernel<<<8192, 256, 0, stream>>>(x, Wq, Wk, Wv, Wo, xb, wqb, wkb, wvb, wob);
  qkv_gemm_kernel<<<dim3(24, 32), 256, 0, stream>>>(xb, wqb, wkb, wvb, bq, bk, bv,
                                                    Qb, Kb, Vtb);
  attn_kernel<<<dim3(16, 32), 256, 0, stream>>>(Qb, Kb, Vtb, Ob);
  oproj_kernel<<<dim3(8, 32), 256, 0, stream>>>(Ob, wob, bo, x, (float*)d_out);
  ln_kernel<<<4096, 256, 0, stream>>>((float*)d_out, gamma, beta);
}

// Round 2
// 159.557 us; speedup vs baseline: 1.2971x; 1.2971x over previous
//
#include <hip/hip_runtime.h>
#include <hip/hip_bf16.h>
#include <cstdint>
#include <cstddef>

// Problem dims
#define NB 2
#define NL 2048
#define NE 1024
#define NH 16
#define ND 64
#define NM (NB * NL)  // 4096 rows total

typedef float f32x4 __attribute__((ext_vector_type(4)));
typedef __bf16 bf16x8 __attribute__((ext_vector_type(8)));

#define DEV static __device__ __forceinline__

DEV f32x4 mfma16(bf16x8 a, bf16x8 b, f32x4 c) {
  return __builtin_amdgcn_mfma_f32_16x16x32_bf16(a, b, c, 0, 0, 0);
}

DEV ushort f2bf(float f) {
  uint32_t u = __float_as_uint(f);
  uint32_t r = (u + 0x7fffu + ((u >> 16) & 1u)) >> 16;
  return (ushort)r;
}

DEV void gl_lds16(const void* src, void* lds_dst) {
  __builtin_amdgcn_global_load_lds(
      (const __attribute__((address_space(1))) void*)src,
      (__attribute__((address_space(3))) void*)lds_dst, 16, 0, 0);
}

// Stage a tile whose rows are 128 bytes (64 bf16) into LDS, linear dest,
// source pre-swizzled with the involution byte ^= ((row&7)<<4) so that
// swizzled ds_read_b128 fragment reads are bank-conflict-reduced.
template <int NCALLS>
DEV void stage_swz(const char* gbase, size_t row_stride_b, char* lds_base, int tid) {
#pragma unroll
  for (int c = 0; c < NCALLS; ++c) {
    uint32_t P = (uint32_t)(c * 4096 + tid * 16);
    uint32_t r = P >> 7;
    uint32_t Lo = P ^ ((r & 7u) << 4);
    gl_lds16(gbase + (size_t)r * row_stride_b + (Lo & 127u), lds_base + P);
  }
}

// ---------------------------------------------------------------- pack
__global__ __launch_bounds__(256) void pack_kernel(
    const float* __restrict__ x, const float* __restrict__ wq,
    const float* __restrict__ wk, const float* __restrict__ wv,
    const float* __restrict__ wo, ushort* __restrict__ xb,
    ushort* __restrict__ wqb, ushort* __restrict__ wkb,
    ushort* __restrict__ wvb, ushort* __restrict__ wob) {
  int64_t q = (int64_t)blockIdx.x * 256 + threadIdx.x;  // quad id, 2097152 total
  const float* src;
  ushort* dst;
  bool cl;
  if (q < 1048576) {
    src = x + q * 4;
    dst = xb + q * 4;
    cl = true;
  } else {
    int64_t r = q - 1048576;
    int wsel = (int)(r >> 18);
    int64_t o = (r & 262143) * 4;
    cl = false;
    if (wsel == 0) { src = wq + o; dst = wqb + o; }
    else if (wsel == 1) { src = wk + o; dst = wkb + o; }
    else if (wsel == 2) { src = wv + o; dst = wvb + o; }
    else { src = wo + o; dst = wob + o; }
  }
  float4 v = *(const float4*)src;
  if (cl) {
    v.x = (v.x != v.x) ? 0.f : fminf(fmaxf(v.x, -1e9f), 1e9f);
    v.y = (v.y != v.y) ? 0.f : fminf(fmaxf(v.y, -1e9f), 1e9f);
    v.z = (v.z != v.z) ? 0.f : fminf(fmaxf(v.z, -1e9f), 1e9f);
    v.w = (v.w != v.w) ? 0.f : fminf(fmaxf(v.w, -1e9f), 1e9f);
  }
  ushort4 o4;
  o4.x = f2bf(v.x);
  o4.y = f2bf(v.y);
  o4.z = f2bf(v.z);
  o4.w = f2bf(v.w);
  *(ushort4*)dst = o4;
}

// ---------------------------------------------------------------- QKV GEMM
// C(4096 x 3072) = xb(4096x1024) @ W^T, scattered epilogue:
//  Q (pre-scaled by 0.125*log2e) -> (B,H,L,D) ; K -> (B,H,L,D) ; V -> (B,H,D,L)
__global__ __launch_bounds__(256) void qkv_gemm_kernel(
    const ushort* __restrict__ xb, const ushort* __restrict__ wqb,
    const ushort* __restrict__ wkb, const ushort* __restrict__ wvb,
    const float* __restrict__ bq, const float* __restrict__ bk,
    const float* __restrict__ bv, ushort* __restrict__ Qo,
    ushort* __restrict__ Ko, ushort* __restrict__ Vto) {
  __shared__ __align__(128) char lds[32768];
  const int tid = threadIdx.x;
  const int w = tid >> 6, ln = tid & 63;
  const int ln15 = ln & 15, g = ln >> 4;
  const int wm = w >> 1, wn = w & 1;
  const int m0 = blockIdx.y * 128;
  const int which = blockIdx.x >> 3;          // 0=Q 1=K 2=V
  const int n0w = (blockIdx.x & 7) * 128;     // within [0,1024)
  const ushort* Wb = (which == 0) ? wqb : (which == 1) ? wkb : wvb;

  const char* Abase = (const char*)xb + (size_t)m0 * 2048;
  const char* Bbase = (const char*)Wb + (size_t)n0w * 2048;

  f32x4 acc[4][4];
#pragma unroll
  for (int m = 0; m < 4; ++m)
#pragma unroll
    for (int n = 0; n < 4; ++n) acc[m][n] = {0.f, 0.f, 0.f, 0.f};

  for (int kt = 0; kt < 1024; kt += 64) {
    __syncthreads();
    stage_swz<4>(Abase + kt * 2, 2048, lds, tid);
    stage_swz<4>(Bbase + kt * 2, 2048, lds + 16384, tid);
    asm volatile("s_waitcnt vmcnt(0)" ::: "memory");
    __syncthreads();
#pragma unroll
    for (int kc = 0; kc < 2; ++kc) {
      bf16x8 af[4], bfr[4];
#pragma unroll
      for (int i = 0; i < 4; ++i) {
        uint32_t ar = (uint32_t)(wm * 64 + i * 16 + ln15);
        uint32_t ao = (ar * 128u + (uint32_t)(kc * 64 + g * 16)) ^ ((ar & 7u) << 4);
        af[i] = *(const bf16x8*)(lds + ao);
        uint32_t br = (uint32_t)(wn * 64 + i * 16 + ln15);
        uint32_t bo_ = 16384u + ((br * 128u + (uint32_t)(kc * 64 + g * 16)) ^ ((br & 7u) << 4));
        bfr[i] = *(const bf16x8*)(lds + bo_);
      }
#pragma unroll
      for (int m = 0; m < 4; ++m)
#pragma unroll
        for (int n = 0; n < 4; ++n) acc[m][n] = mfma16(af[m], bfr[n], acc[m][n]);
    }
  }

  const float* bias = (which == 0) ? bq : (which == 1) ? bk : bv;
  // Q pre-scale: scores use exp2, so fold (1/8)*log2(e) into Q (incl. bias).
  const float sc = (which == 0) ? 0.18033688011112042f : 1.0f;
#pragma unroll
  for (int n = 0; n < 4; ++n) {
    const int col = n0w + wn * 64 + n * 16 + ln15;  // [0,1024)
    const int h = col >> 6, d = col & 63;
    const float bc = bias[col];
#pragma unroll
    for (int m = 0; m < 4; ++m) {
      if (which < 2) {
        ushort* dst = (which == 0) ? Qo : Ko;
#pragma unroll
        for (int j = 0; j < 4; ++j) {
          int mg = m0 + wm * 64 + m * 16 + g * 4 + j;
          int b = mg >> 11, l = mg & 2047;
          dst[((size_t)(b * NH + h) * NL + l) * ND + d] = f2bf((acc[m][n][j] + bc) * sc);
        }
      } else {
        int mg0 = m0 + wm * 64 + m * 16 + g * 4;
        int b = mg0 >> 11, l0 = mg0 & 2047;
        ushort4 pk;
        pk.x = f2bf(acc[m][n][0] + bc);
        pk.y = f2bf(acc[m][n][1] + bc);
        pk.z = f2bf(acc[m][n][2] + bc);
        pk.w = f2bf(acc[m][n][3] + bc);
        *(ushort4*)(Vto + ((size_t)(b * NH + h) * ND + d) * NL + l0) = pk;
      }
    }
  }
}

// ---------------------------------------------------------------- attention
// Balanced causal flash attention.
// Block = one (b,h) and a PAIR of 64-row q-tiles (p, 31-p): uniform 33 KV steps.
// 4 waves x 16 q-rows. K/V double-buffered in LDS with prefetch; P wave-private.
__global__ __launch_bounds__(256) void attn_kernel(
    const ushort* __restrict__ Q, const ushort* __restrict__ K,
    const ushort* __restrict__ Vt, ushort* __restrict__ Op) {
  __shared__ __align__(128) char lds[40960];  // K dbuf 16K | V dbuf 16K | P 4x2K
  const int tid = threadIdx.x;
  const int w = tid >> 6, ln = tid & 63;
  const int ln15 = ln & 15, g = ln >> 4;
  // XCD-aware: 4 consecutive bh per XCD so K/V working set (2MB) fits L2.
  const int bx = blockIdx.x;           // [0,512)
  const int xcd = bx & 7, rr = bx >> 3;
  const int pr = rr & 15, bl = rr >> 4;
  const int bh = xcd * 4 + bl;         // [0,32)
  const int b = bh >> 4, h = bh & 15;
  const ushort* Qh = Q + (size_t)bh * NL * ND;
  const ushort* Kh = K + (size_t)bh * NL * ND;
  const ushort* Vth = Vt + (size_t)bh * ND * NL;
  const uint32_t pbase = 32768u + (uint32_t)w * 2048u;

  for (int phase = 0; phase < 2; ++phase) {
    const int qt = phase ? (31 - pr) : pr;   // paired: total steps uniform (33)
    const int qb = qt * 64;
    const int r0 = qb + w * 16;              // this wave's first q row
    const int nt = qt + 1;                   // KV tiles of 64

    bf16x8 qf[2];
#pragma unroll
    for (int kc = 0; kc < 2; ++kc)
      qf[kc] = *(const bf16x8*)(Qh + (size_t)(r0 + ln15) * ND + kc * 32 + g * 8);

    f32x4 o_acc[4];
    float m_run[4], l_run[4];
#pragma unroll
    for (int n = 0; n < 4; ++n) o_acc[n] = {0.f, 0.f, 0.f, 0.f};
#pragma unroll
    for (int j = 0; j < 4; ++j) {
      m_run[j] = -1e30f;
      l_run[j] = 0.f;
    }

    int cur = 0;
    stage_swz<2>((const char*)Kh, 128, lds, tid);
    stage_swz<2>((const char*)Vth, (size_t)NL * 2, lds + 16384, tid);
    __syncthreads();

    for (int t = 0; t < nt; ++t) {
      const int s0 = t * 64;
      if (t + 1 < nt) {  // prefetch next K/V tile into the other buffer
        stage_swz<2>((const char*)Kh + (size_t)(s0 + 64) * 128, 128,
                     lds + (cur ^ 1) * 8192, tid);
        stage_swz<2>((const char*)Vth + (size_t)(s0 + 64) * 2, (size_t)NL * 2,
                     lds + 16384 + (cur ^ 1) * 8192, tid);
      }
      const char* kb = lds + cur * 8192;
      const char* vb = lds + 16384 + cur * 8192;

      // S = Q K^T (16 q-rows x 64 kv-cols per wave), Q pre-scaled to log2 units
      f32x4 s_acc[4];
#pragma unroll
      for (int n = 0; n < 4; ++n) s_acc[n] = {0.f, 0.f, 0.f, 0.f};
      __builtin_amdgcn_s_setprio(1);
#pragma unroll
      for (int kc = 0; kc < 2; ++kc) {
        bf16x8 kf[4];
#pragma unroll
        for (int n = 0; n < 4; ++n) {
          uint32_t kr = (uint32_t)(n * 16 + ln15);
          uint32_t off = (kr * 128u + (uint32_t)(kc * 64 + g * 16)) ^ ((kr & 7u) << 4);
          kf[n] = *(const bf16x8*)(kb + off);
        }
#pragma unroll
        for (int n = 0; n < 4; ++n) s_acc[n] = mfma16(qf[kc], kf[n], s_acc[n]);
      }
      __builtin_amdgcn_s_setprio(0);

      // causal mask only on the (single, block-uniform) diagonal tile
      if (s0 == qb) {
#pragma unroll
        for (int n = 0; n < 4; ++n)
#pragma unroll
          for (int j = 0; j < 4; ++j) {
            int qi = r0 + g * 4 + j;
            int si = s0 + n * 16 + ln15;
            s_acc[n][j] = (si > qi) ? -1e30f : s_acc[n][j];
          }
      }

      // online softmax (log2 domain), defer-max with THR=8 (P <= 2^8)
      float mx[4] = {-1e30f, -1e30f, -1e30f, -1e30f};
#pragma unroll
      for (int n = 0; n < 4; ++n)
#pragma unroll
        for (int j = 0; j < 4; ++j) mx[j] = fmaxf(mx[j], s_acc[n][j]);
#pragma unroll
      for (int j = 0; j < 4; ++j)
#pragma unroll
        for (int dd = 1; dd < 16; dd <<= 1) mx[j] = fmaxf(mx[j], __shfl_xor(mx[j], dd));
      bool need = false;
#pragma unroll
      for (int j = 0; j < 4; ++j) need |= (mx[j] > m_run[j] + 8.0f);
      if (__any(need)) {
#pragma unroll
        for (int j = 0; j < 4; ++j) {
          float mn = fmaxf(m_run[j], mx[j]);
          float al = exp2f(m_run[j] - mn);
          m_run[j] = mn;
          l_run[j] *= al;
#pragma unroll
          for (int n = 0; n < 4; ++n) o_acc[n][j] *= al;
        }
      }
      float ps[4] = {0.f, 0.f, 0.f, 0.f};
#pragma unroll
      for (int n = 0; n < 4; ++n)
#pragma unroll
        for (int j = 0; j < 4; ++j) {
          float pv = exp2f(s_acc[n][j] - m_run[j]);
          ps[j] += pv;
          uint32_t prow = (uint32_t)(g * 4 + j);
          uint32_t off = (prow * 128u + (uint32_t)((n * 16 + ln15) * 2)) ^ ((prow & 7u) << 4);
          *(ushort*)(lds + pbase + off) = f2bf(pv);
        }
#pragma unroll
      for (int j = 0; j < 4; ++j) {
#pragma unroll
        for (int dd = 1; dd < 16; dd <<= 1) ps[j] += __shfl_xor(ps[j], dd);
        l_run[j] += ps[j];
      }

      // O += P V  (P wave-private: no barrier needed before reads)
      __builtin_amdgcn_s_setprio(1);
#pragma unroll
      for (int kc = 0; kc < 2; ++kc) {
        uint32_t poff = ((uint32_t)ln15 * 128u + (uint32_t)(kc * 64 + g * 16)) ^
                        (((uint32_t)ln15 & 7u) << 4);
        bf16x8 pf = *(const bf16x8*)(lds + pbase + poff);
        bf16x8 vf[4];
#pragma unroll
        for (int n = 0; n < 4; ++n) {
          uint32_t vr = (uint32_t)(n * 16 + ln15);
          uint32_t off = (vr * 128u + (uint32_t)(kc * 64 + g * 16)) ^ ((vr & 7u) << 4);
          vf[n] = *(const bf16x8*)(vb + off);
        }
#pragma unroll
        for (int n = 0; n < 4; ++n) o_acc[n] = mfma16(pf, vf[n], o_acc[n]);
      }
      __builtin_amdgcn_s_setprio(0);

      __syncthreads();  // all reads of buf[cur] done; prefetch (vmcnt) drained
      cur ^= 1;
    }

    // write O (bf16) packed as (B*L, E)
#pragma unroll
    for (int j = 0; j < 4; ++j) {
      float inv = 1.0f / l_run[j];
      int qi = r0 + g * 4 + j;
      size_t rowo = ((size_t)b * NL + qi) * NE + h * ND;
#pragma unroll
      for (int n = 0; n < 4; ++n) Op[rowo + n * 16 + ln15] = f2bf(o_acc[n][j] * inv);
    }
  }
}

// ---------------------------------------------------------------- out-proj + residual
__global__ __launch_bounds__(256) void oproj_kernel(
    const ushort* __restrict__ ob, const ushort* __restrict__ wob,
    const float* __restrict__ bo, const float* __restrict__ x,
    float* __restrict__ out) {
  __shared__ __align__(128) char lds[32768];
  const int tid = threadIdx.x;
  const int w = tid >> 6, ln = tid & 63;
  const int ln15 = ln & 15, g = ln >> 4;
  const int wm = w >> 1, wn = w & 1;
  const int m0 = blockIdx.y * 128;
  const int n0 = blockIdx.x * 128;

  const char* Abase = (const char*)ob + (size_t)m0 * 2048;
  const char* Bbase = (const char*)wob + (size_t)n0 * 2048;

  f32x4 acc[4][4];
#pragma unroll
  for (int m = 0; m < 4; ++m)
#pragma unroll
    for (int n = 0; n < 4; ++n) acc[m][n] = {0.f, 0.f, 0.f, 0.f};

  for (int kt = 0; kt < 1024; kt += 64) {
    __syncthreads();
    stage_swz<4>(Abase + kt * 2, 2048, lds, tid);
    stage_swz<4>(Bbase + kt * 2, 2048, lds + 16384, tid);
    asm volatile("s_waitcnt vmcnt(0)" ::: "memory");
    __syncthreads();
#pragma unroll
    for (int kc = 0; kc < 2; ++kc) {
      bf16x8 af[4], bfr[4];
#pragma unroll
      for (int i = 0; i < 4; ++i) {
        uint32_t ar = (uint32_t)(wm * 64 + i * 16 + ln15);
        uint32_t ao = (ar * 128u + (uint32_t)(kc * 64 + g * 16)) ^ ((ar & 7u) << 4);
        af[i] = *(const bf16x8*)(lds + ao);
        uint32_t br = (uint32_t)(wn * 64 + i * 16 + ln15);
        uint32_t bo_ = 16384u + ((br * 128u + (uint32_t)(kc * 64 + g * 16)) ^ ((br & 7u) << 4));
        bfr[i] = *(const bf16x8*)(lds + bo_);
      }
#pragma unroll
      for (int m = 0; m < 4; ++m)
#pragma unroll
        for (int n = 0; n < 4; ++n) acc[m][n] = mfma16(af[m], bfr[n], acc[m][n]);
    }
  }

#pragma unroll
  for (int n = 0; n < 4; ++n) {
    const int col = n0 + wn * 64 + n * 16 + ln15;
    const float bc = bo[col];
#pragma unroll
    for (int m = 0; m < 4; ++m)
#pragma unroll
      for (int j = 0; j < 4; ++j) {
        int mg = m0 + wm * 64 + m * 16 + g * 4 + j;
        size_t idx = (size_t)mg * NE + col;
        out[idx] = acc[m][n][j] + bc + x[idx];
      }
  }
}

// ---------------------------------------------------------------- LayerNorm (in-place)
__global__ __launch_bounds__(256) void ln_kernel(float* __restrict__ io,
                                                 const float* __restrict__ gamma,
                                                 const float* __restrict__ beta) {
  const int row = blockIdx.x, tid = threadIdx.x;
  const int w = tid >> 6, ln = tid & 63;
  float4 v = *(const float4*)(io + (size_t)row * NE + tid * 4);
  float s = v.x + v.y + v.z + v.w;
  float ss = v.x * v.x + v.y * v.y + v.z * v.z + v.w * v.w;
#pragma unroll
  for (int d = 1; d < 64; d <<= 1) {
    s += __shfl_xor(s, d);
    ss += __shfl_xor(ss, d);
  }
  __shared__ float red[8];
  if (ln == 0) {
    red[w] = s;
    red[4 + w] = ss;
  }
  __syncthreads();
  s = red[0] + red[1] + red[2] + red[3];
  ss = red[4] + red[5] + red[6] + red[7];
  const float mu = s * (1.0f / (float)NE);
  float var = ss * (1.0f / (float)NE) - mu * mu;
  const float inv = rsqrtf(var + 1e-5f);
  float4 gv = *(const float4*)(gamma + tid * 4);
  float4 bv = *(const float4*)(beta + tid * 4);
  float4 o;
  o.x = (v.x - mu) * inv * gv.x + bv.x;
  o.y = (v.y - mu) * inv * gv.y + bv.y;
  o.z = (v.z - mu) * inv * gv.z + bv.z;
  o.w = (v.w - mu) * inv * gv.w + bv.w;
  *(float4*)(io + (size_t)row * NE + tid * 4) = o;
}

// ---------------------------------------------------------------- launch
extern "C" void kernel_launch(void* const* d_in, const int* in_sizes, int n_in,
                              void* d_out, int out_size, void* d_ws, size_t ws_size,
                              hipStream_t stream) {
  const float* x = (const float*)d_in[0];
  // d_in[1] = mask (causal, recomputed analytically -> unused)
  const float* Wq = (const float*)d_in[2];
  const float* bq = (const float*)d_in[3];
  const float* Wk = (const float*)d_in[4];
  const float* bk = (const float*)d_in[5];
  const float* Wv = (const float*)d_in[6];
  const float* bv = (const float*)d_in[7];
  const float* Wo = (const float*)d_in[8];
  const float* bo = (const float*)d_in[9];
  const float* gamma = (const float*)d_in[10];
  const float* beta = (const float*)d_in[11];

  char* ws = (char*)d_ws;
  ushort* xb  = (ushort*)(ws + 0);          // 8 MB  (4096x1024 bf16)
  ushort* wqb = (ushort*)(ws + 8388608);    // 2 MB
  ushort* wkb = (ushort*)(ws + 10485760);   // 2 MB
  ushort* wvb = (ushort*)(ws + 12582912);   // 2 MB
  ushort* wob = (ushort*)(ws + 14680064);   // 2 MB
  ushort* Qb  = (ushort*)(ws + 16777216);   // 8 MB (B,H,L,D) pre-scaled
  ushort* Kb  = (ushort*)(ws + 25165824);   // 8 MB (B,H,L,D)
  ushort* Vtb = (ushort*)(ws + 33554432);   // 8 MB (B,H,D,L)
  ushort* Ob  = (ushort*)(ws + 41943040);   // 8 MB (B*L, E)

  pack_kernel<<<8192, 256, 0, stream>>>(x, Wq, Wk, Wv, Wo, xb, wqb, wkb, wvb, wob);
  qkv_gemm_kernel<<<dim3(24, 32), 256, 0, stream>>>(xb, wqb, wkb, wvb, bq, bk, bv,
                                                    Qb, Kb, Vtb);
  attn_kernel<<<512, 256, 0, stream>>>(Qb, Kb, Vtb, Ob);
  oproj_kernel<<<dim3(8, 32), 256, 0, stream>>>(Ob, wob, bo, x, (float*)d_out);
  ln_kernel<<<4096, 256, 0, stream>>>((float*)d_out, gamma, beta);
}

// Round 3
// 131.638 us; speedup vs baseline: 1.5722x; 1.2121x over previous
//
#include <hip/hip_runtime.h>
#include <hip/hip_bf16.h>
#include <cstdint>
#include <cstddef>

// Problem dims
#define NB 2
#define NL 2048
#define NE 1024
#define NH 16
#define ND 64
#define NM (NB * NL)  // 4096 rows total

typedef float f32x4 __attribute__((ext_vector_type(4)));
typedef __bf16 bf16x8 __attribute__((ext_vector_type(8)));
typedef __bf16 bf16x4 __attribute__((ext_vector_type(4)));

#define DEV static __device__ __forceinline__

DEV f32x4 mfma16(bf16x8 a, bf16x8 b, f32x4 c) {
  return __builtin_amdgcn_mfma_f32_16x16x32_bf16(a, b, c, 0, 0, 0);
}

DEV ushort f2bf(float f) {
  uint32_t u = __float_as_uint(f);
  uint32_t r = (u + 0x7fffu + ((u >> 16) & 1u)) >> 16;
  return (ushort)r;
}

#if __has_builtin(__builtin_amdgcn_exp2f)
DEV float fast_exp2(float x) { return __builtin_amdgcn_exp2f(x); }
#else
DEV float fast_exp2(float x) { return exp2f(x); }
#endif

DEV void gl_lds16(const void* src, void* lds_dst) {
  __builtin_amdgcn_global_load_lds(
      (const __attribute__((address_space(1))) void*)src,
      (__attribute__((address_space(3))) void*)lds_dst, 16, 0, 0);
}

// Stage a tile whose rows are 128 bytes (64 bf16) into LDS, linear dest,
// source pre-swizzled with the involution byte ^= ((row&7)<<4) so that
// swizzled ds_read_b128 fragment reads are bank-conflict-reduced.
template <int NCALLS>
DEV void stage_swz(const char* gbase, size_t row_stride_b, char* lds_base, int tid) {
#pragma unroll
  for (int c = 0; c < NCALLS; ++c) {
    uint32_t P = (uint32_t)(c * 4096 + tid * 16);
    uint32_t r = P >> 7;
    uint32_t Lo = P ^ ((r & 7u) << 4);
    gl_lds16(gbase + (size_t)r * row_stride_b + (Lo & 127u), lds_base + P);
  }
}

// ---------------------------------------------------------------- pack
__global__ __launch_bounds__(256) void pack_kernel(
    const float* __restrict__ x, const float* __restrict__ wq,
    const float* __restrict__ wk, const float* __restrict__ wv,
    const float* __restrict__ wo, ushort* __restrict__ xb,
    ushort* __restrict__ wqb, ushort* __restrict__ wkb,
    ushort* __restrict__ wvb, ushort* __restrict__ wob) {
  int64_t q = (int64_t)blockIdx.x * 256 + threadIdx.x;  // quad id, 2097152 total
  const float* src;
  ushort* dst;
  bool cl;
  if (q < 1048576) {
    src = x + q * 4;
    dst = xb + q * 4;
    cl = true;
  } else {
    int64_t r = q - 1048576;
    int wsel = (int)(r >> 18);
    int64_t o = (r & 262143) * 4;
    cl = false;
    if (wsel == 0) { src = wq + o; dst = wqb + o; }
    else if (wsel == 1) { src = wk + o; dst = wkb + o; }
    else if (wsel == 2) { src = wv + o; dst = wvb + o; }
    else { src = wo + o; dst = wob + o; }
  }
  float4 v = *(const float4*)src;
  if (cl) {
    v.x = (v.x != v.x) ? 0.f : fminf(fmaxf(v.x, -1e9f), 1e9f);
    v.y = (v.y != v.y) ? 0.f : fminf(fmaxf(v.y, -1e9f), 1e9f);
    v.z = (v.z != v.z) ? 0.f : fminf(fmaxf(v.z, -1e9f), 1e9f);
    v.w = (v.w != v.w) ? 0.f : fminf(fmaxf(v.w, -1e9f), 1e9f);
  }
  ushort4 o4;
  o4.x = f2bf(v.x);
  o4.y = f2bf(v.y);
  o4.z = f2bf(v.z);
  o4.w = f2bf(v.w);
  *(ushort4*)dst = o4;
}

// ---------------------------------------------------------------- QKV GEMM
// C(4096 x 3072) = xb(4096x1024) @ W^T, scattered epilogue:
//  Q (pre-scaled by 0.125*log2e) -> (B,H,L,D) ; K -> (B,H,L,D) ; V -> (B,H,D,L)
__global__ __launch_bounds__(256) void qkv_gemm_kernel(
    const ushort* __restrict__ xb, const ushort* __restrict__ wqb,
    const ushort* __restrict__ wkb, const ushort* __restrict__ wvb,
    const float* __restrict__ bq, const float* __restrict__ bk,
    const float* __restrict__ bv, ushort* __restrict__ Qo,
    ushort* __restrict__ Ko, ushort* __restrict__ Vto) {
  __shared__ __align__(128) char lds[32768];
  const int tid = threadIdx.x;
  const int w = tid >> 6, ln = tid & 63;
  const int ln15 = ln & 15, g = ln >> 4;
  const int wm = w >> 1, wn = w & 1;
  const int m0 = blockIdx.y * 128;
  const int which = blockIdx.x >> 3;          // 0=Q 1=K 2=V
  const int n0w = (blockIdx.x & 7) * 128;     // within [0,1024)
  const ushort* Wb = (which == 0) ? wqb : (which == 1) ? wkb : wvb;

  const char* Abase = (const char*)xb + (size_t)m0 * 2048;
  const char* Bbase = (const char*)Wb + (size_t)n0w * 2048;

  f32x4 acc[4][4];
#pragma unroll
  for (int m = 0; m < 4; ++m)
#pragma unroll
    for (int n = 0; n < 4; ++n) acc[m][n] = {0.f, 0.f, 0.f, 0.f};

  for (int kt = 0; kt < 1024; kt += 64) {
    __syncthreads();
    stage_swz<4>(Abase + kt * 2, 2048, lds, tid);
    stage_swz<4>(Bbase + kt * 2, 2048, lds + 16384, tid);
    asm volatile("s_waitcnt vmcnt(0)" ::: "memory");
    __syncthreads();
#pragma unroll
    for (int kc = 0; kc < 2; ++kc) {
      bf16x8 af[4], bfr[4];
#pragma unroll
      for (int i = 0; i < 4; ++i) {
        uint32_t ar = (uint32_t)(wm * 64 + i * 16 + ln15);
        uint32_t ao = (ar * 128u + (uint32_t)(kc * 64 + g * 16)) ^ ((ar & 7u) << 4);
        af[i] = *(const bf16x8*)(lds + ao);
        uint32_t br = (uint32_t)(wn * 64 + i * 16 + ln15);
        uint32_t bo_ = 16384u + ((br * 128u + (uint32_t)(kc * 64 + g * 16)) ^ ((br & 7u) << 4));
        bfr[i] = *(const bf16x8*)(lds + bo_);
      }
#pragma unroll
      for (int m = 0; m < 4; ++m)
#pragma unroll
        for (int n = 0; n < 4; ++n) acc[m][n] = mfma16(af[m], bfr[n], acc[m][n]);
    }
  }

  const float* bias = (which == 0) ? bq : (which == 1) ? bk : bv;
  // Q pre-scale: scores use exp2, so fold (1/8)*log2(e) into Q (incl. bias).
  const float sc = (which == 0) ? 0.18033688011112042f : 1.0f;
#pragma unroll
  for (int n = 0; n < 4; ++n) {
    const int col = n0w + wn * 64 + n * 16 + ln15;  // [0,1024)
    const int h = col >> 6, d = col & 63;
    const float bc = bias[col];
#pragma unroll
    for (int m = 0; m < 4; ++m) {
      if (which < 2) {
        ushort* dst = (which == 0) ? Qo : Ko;
#pragma unroll
        for (int j = 0; j < 4; ++j) {
          int mg = m0 + wm * 64 + m * 16 + g * 4 + j;
          int b = mg >> 11, l = mg & 2047;
          dst[((size_t)(b * NH + h) * NL + l) * ND + d] = f2bf((acc[m][n][j] + bc) * sc);
        }
      } else {
        int mg0 = m0 + wm * 64 + m * 16 + g * 4;
        int b = mg0 >> 11, l0 = mg0 & 2047;
        ushort4 pk;
        pk.x = f2bf(acc[m][n][0] + bc);
        pk.y = f2bf(acc[m][n][1] + bc);
        pk.z = f2bf(acc[m][n][2] + bc);
        pk.w = f2bf(acc[m][n][3] + bc);
        *(ushort4*)(Vto + ((size_t)(b * NH + h) * ND + d) * NL + l0) = pk;
      }
    }
  }
}

// ---------------------------------------------------------------- attention
// Causal flash attention. 1024 blocks, one (b,h, 64-row q-tile) each; 4 waves
// x 16 q-rows. Swapped QK^T (S^T in regs -> in-lane softmax). K/V double-
// buffered in LDS; counted vmcnt keeps prefetch in flight across barriers.
// Block mapping: co-resident sets {bx,bx+256,bx+512,bx+768} sum to 66 steps.
__global__ __launch_bounds__(256) void attn_kernel(
    const ushort* __restrict__ Q, const ushort* __restrict__ K,
    const ushort* __restrict__ Vt, ushort* __restrict__ Op) {
  __shared__ __align__(128) char lds[40960];  // K dbuf 16K | V dbuf 16K | P 4x2K
  const int tid = threadIdx.x;
  const int w = tid >> 6, ln = tid & 63;
  const int ln15 = ln & 15, g = ln >> 4;
  const int bx = blockIdx.x;  // [0,1024)
  const int kk = (bx >> 5) & 7, bsel = bx >> 8, bh = bx & 31;
  const int qt = (bsel == 0) ? 31 - kk : (bsel == 1) ? kk
               : (bsel == 2) ? 23 - kk : 8 + kk;
  const int b = bh >> 4, h = bh & 15;
  const ushort* Qh = Q + (size_t)bh * NL * ND;
  const ushort* Kh = K + (size_t)bh * NL * ND;
  const ushort* Vth = Vt + (size_t)bh * ND * NL;
  const uint32_t pbase = 32768u + (uint32_t)w * 2048u;

  const int qb = qt * 64;
  const int r0 = qb + w * 16;  // this wave's first q row
  const int nt = qt + 1;       // KV tiles of 64

  bf16x8 qf[2];
#pragma unroll
  for (int kc = 0; kc < 2; ++kc)
    qf[kc] = *(const bf16x8*)(Qh + (size_t)(r0 + ln15) * ND + kc * 32 + g * 8);

  f32x4 o_acc[4];
#pragma unroll
  for (int n = 0; n < 4; ++n) o_acc[n] = {0.f, 0.f, 0.f, 0.f};
  float m_run = -1e30f, l_run = 0.f;  // per-lane: stats of q-row r0+ln15

  int cur = 0;
  stage_swz<2>((const char*)Kh, 128, lds, tid);
  stage_swz<2>((const char*)Vth, (size_t)NL * 2, lds + 16384, tid);

  for (int t = 0; t < nt; ++t) {
    const int s0 = t * 64;
    if (t + 1 < nt) {  // prefetch next K/V tile; keep in flight across barrier
      stage_swz<2>((const char*)Kh + (size_t)(s0 + 64) * 128, 128,
                   lds + (cur ^ 1) * 8192, tid);
      stage_swz<2>((const char*)Vth + (size_t)(s0 + 64) * 2, (size_t)NL * 2,
                   lds + 16384 + (cur ^ 1) * 8192, tid);
      asm volatile("s_waitcnt vmcnt(4)" ::: "memory");  // tile t landed; 4 stay
    } else {
      asm volatile("s_waitcnt vmcnt(0)" ::: "memory");
    }
    __builtin_amdgcn_s_barrier();
    asm volatile("" ::: "memory");

    const char* kb = lds + cur * 8192;
    const char* vb = lds + 16384 + cur * 8192;

    // S^T = K Q^T : s_acc[n][j] holds k = s0+n*16+g*4+j, q = r0+ln15
    f32x4 s_acc[4];
#pragma unroll
    for (int n = 0; n < 4; ++n) s_acc[n] = {0.f, 0.f, 0.f, 0.f};
    __builtin_amdgcn_s_setprio(1);
#pragma unroll
    for (int kc = 0; kc < 2; ++kc) {
      bf16x8 kf[4];
#pragma unroll
      for (int n = 0; n < 4; ++n) {
        uint32_t kr = (uint32_t)(n * 16 + ln15);
        uint32_t off = (kr * 128u + (uint32_t)(kc * 64 + g * 16)) ^ ((kr & 7u) << 4);
        kf[n] = *(const bf16x8*)(kb + off);
      }
#pragma unroll
      for (int n = 0; n < 4; ++n) s_acc[n] = mfma16(kf[n], qf[kc], s_acc[n]);
    }
    __builtin_amdgcn_s_setprio(0);

    // causal mask only on the (last, block-uniform) diagonal tile
    if (t == nt - 1) {
      const int qi = r0 + ln15;
#pragma unroll
      for (int n = 0; n < 4; ++n)
#pragma unroll
        for (int j = 0; j < 4; ++j) {
          int si = s0 + n * 16 + g * 4 + j;
          s_acc[n][j] = (si > qi) ? -1e30f : s_acc[n][j];
        }
    }

    // online softmax, fully in-lane over 16 k-values + 2-step cross-g reduce
    float mx = s_acc[0][0];
#pragma unroll
    for (int n = 0; n < 4; ++n)
#pragma unroll
      for (int j = 0; j < 4; ++j) mx = fmaxf(mx, s_acc[n][j]);
    mx = fmaxf(mx, __shfl_xor(mx, 16));
    mx = fmaxf(mx, __shfl_xor(mx, 32));
    if (__any(mx > m_run + 8.0f)) {  // defer-max: P bounded by 2^8
      float mn = fmaxf(m_run, mx);
      float al = fast_exp2(m_run - mn);
      m_run = mn;
      l_run *= al;
#pragma unroll
      for (int j = 0; j < 4; ++j) {
        float aj = __shfl(al, g * 4 + j);  // alpha of q-row g*4+j
#pragma unroll
        for (int n = 0; n < 4; ++n) o_acc[n][j] *= aj;
      }
    }
    float ps = 0.f;
#pragma unroll
    for (int n = 0; n < 4; ++n) {
      float p0 = fast_exp2(s_acc[n][0] - m_run);
      float p1 = fast_exp2(s_acc[n][1] - m_run);
      float p2 = fast_exp2(s_acc[n][2] - m_run);
      float p3 = fast_exp2(s_acc[n][3] - m_run);
      ps += (p0 + p1) + (p2 + p3);
      bf16x4 pk = {(__bf16)p0, (__bf16)p1, (__bf16)p2, (__bf16)p3};
      // P[q=ln15][k=n*16+g*4 .. +3], row-swizzled like K/V
      uint32_t off = ((uint32_t)ln15 * 128u + (uint32_t)(n * 32 + g * 8)) ^
                     (((uint32_t)ln15 & 7u) << 4);
      *(bf16x4*)(lds + pbase + off) = pk;
    }
    ps += __shfl_xor(ps, 16);
    ps += __shfl_xor(ps, 32);
    l_run += ps;

    // O += P V  (P wave-private)
    __builtin_amdgcn_s_setprio(1);
#pragma unroll
    for (int kc = 0; kc < 2; ++kc) {
      uint32_t poff = ((uint32_t)ln15 * 128u + (uint32_t)(kc * 64 + g * 16)) ^
                      (((uint32_t)ln15 & 7u) << 4);
      bf16x8 pf = *(const bf16x8*)(lds + pbase + poff);
      bf16x8 vf[4];
#pragma unroll
      for (int n = 0; n < 4; ++n) {
        uint32_t vr = (uint32_t)(n * 16 + ln15);
        uint32_t off = (vr * 128u + (uint32_t)(kc * 64 + g * 16)) ^ ((vr & 7u) << 4);
        vf[n] = *(const bf16x8*)(vb + off);
      }
#pragma unroll
      for (int n = 0; n < 4; ++n) o_acc[n] = mfma16(pf, vf[n], o_acc[n]);
    }
    __builtin_amdgcn_s_setprio(0);

    // my LDS reads delivered; then all waves synced before next overwrite
    asm volatile("s_waitcnt lgkmcnt(0)" ::: "memory");
    __builtin_amdgcn_s_barrier();
    asm volatile("" ::: "memory");
    cur ^= 1;
  }

  // write O (bf16) packed as (B*L, E). o_acc[n][j]: q=r0+g*4+j, d=n*16+ln15
  float invl = 1.0f / l_run;
#pragma unroll
  for (int j = 0; j < 4; ++j) {
    float inv = __shfl(invl, g * 4 + j);
    int qi = r0 + g * 4 + j;
    size_t rowo = ((size_t)b * NL + qi) * NE + h * ND;
#pragma unroll
    for (int n = 0; n < 4; ++n) Op[rowo + n * 16 + ln15] = f2bf(o_acc[n][j] * inv);
  }
}

// ---------------------------------------------------------------- out-proj + residual
__global__ __launch_bounds__(256) void oproj_kernel(
    const ushort* __restrict__ ob, const ushort* __restrict__ wob,
    const float* __restrict__ bo, const float* __restrict__ x,
    float* __restrict__ out) {
  __shared__ __align__(128) char lds[32768];
  const int tid = threadIdx.x;
  const int w = tid >> 6, ln = tid & 63;
  const int ln15 = ln & 15, g = ln >> 4;
  const int wm = w >> 1, wn = w & 1;
  const int m0 = blockIdx.y * 128;
  const int n0 = blockIdx.x * 128;

  const char* Abase = (const char*)ob + (size_t)m0 * 2048;
  const char* Bbase = (const char*)wob + (size_t)n0 * 2048;

  f32x4 acc[4][4];
#pragma unroll
  for (int m = 0; m < 4; ++m)
#pragma unroll
    for (int n = 0; n < 4; ++n) acc[m][n] = {0.f, 0.f, 0.f, 0.f};

  for (int kt = 0; kt < 1024; kt += 64) {
    __syncthreads();
    stage_swz<4>(Abase + kt * 2, 2048, lds, tid);
    stage_swz<4>(Bbase + kt * 2, 2048, lds + 16384, tid);
    asm volatile("s_waitcnt vmcnt(0)" ::: "memory");
    __syncthreads();
#pragma unroll
    for (int kc = 0; kc < 2; ++kc) {
      bf16x8 af[4], bfr[4];
#pragma unroll
      for (int i = 0; i < 4; ++i) {
        uint32_t ar = (uint32_t)(wm * 64 + i * 16 + ln15);
        uint32_t ao = (ar * 128u + (uint32_t)(kc * 64 + g * 16)) ^ ((ar & 7u) << 4);
        af[i] = *(const bf16x8*)(lds + ao);
        uint32_t br = (uint32_t)(wn * 64 + i * 16 + ln15);
        uint32_t bo_ = 16384u + ((br * 128u + (uint32_t)(kc * 64 + g * 16)) ^ ((br & 7u) << 4));
        bfr[i] = *(const bf16x8*)(lds + bo_);
      }
#pragma unroll
      for (int m = 0; m < 4; ++m)
#pragma unroll
        for (int n = 0; n < 4; ++n) acc[m][n] = mfma16(af[m], bfr[n], acc[m][n]);
    }
  }

#pragma unroll
  for (int n = 0; n < 4; ++n) {
    const int col = n0 + wn * 64 + n * 16 + ln15;
    const float bc = bo[col];
#pragma unroll
    for (int m = 0; m < 4; ++m)
#pragma unroll
      for (int j = 0; j < 4; ++j) {
        int mg = m0 + wm * 64 + m * 16 + g * 4 + j;
        size_t idx = (size_t)mg * NE + col;
        out[idx] = acc[m][n][j] + bc + x[idx];
      }
  }
}

// ---------------------------------------------------------------- LayerNorm (in-place)
__global__ __launch_bounds__(256) void ln_kernel(float* __restrict__ io,
                                                 const float* __restrict__ gamma,
                                                 const float* __restrict__ beta) {
  const int row = blockIdx.x, tid = threadIdx.x;
  const int w = tid >> 6, ln = tid & 63;
  float4 v = *(const float4*)(io + (size_t)row * NE + tid * 4);
  float s = v.x + v.y + v.z + v.w;
  float ss = v.x * v.x + v.y * v.y + v.z * v.z + v.w * v.w;
#pragma unroll
  for (int d = 1; d < 64; d <<= 1) {
    s += __shfl_xor(s, d);
    ss += __shfl_xor(ss, d);
  }
  __shared__ float red[8];
  if (ln == 0) {
    red[w] = s;
    red[4 + w] = ss;
  }
  __syncthreads();
  s = red[0] + red[1] + red[2] + red[3];
  ss = red[4] + red[5] + red[6] + red[7];
  const float mu = s * (1.0f / (float)NE);
  float var = ss * (1.0f / (float)NE) - mu * mu;
  const float inv = rsqrtf(var + 1e-5f);
  float4 gv = *(const float4*)(gamma + tid * 4);
  float4 bv = *(const float4*)(beta + tid * 4);
  float4 o;
  o.x = (v.x - mu) * inv * gv.x + bv.x;
  o.y = (v.y - mu) * inv * gv.y + bv.y;
  o.z = (v.z - mu) * inv * gv.z + bv.z;
  o.w = (v.w - mu) * inv * gv.w + bv.w;
  *(float4*)(io + (size_t)row * NE + tid * 4) = o;
}

// ---------------------------------------------------------------- launch
extern "C" void kernel_launch(void* const* d_in, const int* in_sizes, int n_in,
                              void* d_out, int out_size, void* d_ws, size_t ws_size,
                              hipStream_t stream) {
  const float* x = (const float*)d_in[0];
  // d_in[1] = mask (causal, recomputed analytically -> unused)
  const float* Wq = (const float*)d_in[2];
  const float* bq = (const float*)d_in[3];
  const float* Wk = (const float*)d_in[4];
  const float* bk = (const float*)d_in[5];
  const float* Wv = (const float*)d_in[6];
  const float* bv = (const float*)d_in[7];
  const float* Wo = (const float*)d_in[8];
  const float* bo = (const float*)d_in[9];
  const float* gamma = (const float*)d_in[10];
  const float* beta = (const float*)d_in[11];

  char* ws = (char*)d_ws;
  ushort* xb  = (ushort*)(ws + 0);          // 8 MB  (4096x1024 bf16)
  ushort* wqb = (ushort*)(ws + 8388608);    // 2 MB
  ushort* wkb = (ushort*)(ws + 10485760);   // 2 MB
  ushort* wvb = (ushort*)(ws + 12582912);   // 2 MB
  ushort* wob = (ushort*)(ws + 14680064);   // 2 MB
  ushort* Qb  = (ushort*)(ws + 16777216);   // 8 MB (B,H,L,D) pre-scaled
  ushort* Kb  = (ushort*)(ws + 25165824);   // 8 MB (B,H,L,D)
  ushort* Vtb = (ushort*)(ws + 33554432);   // 8 MB (B,H,D,L)
  ushort* Ob  = (ushort*)(ws + 41943040);   // 8 MB (B*L, E)

  pack_kernel<<<8192, 256, 0, stream>>>(x, Wq, Wk, Wv, Wo, xb, wqb, wkb, wvb, wob);
  qkv_gemm_kernel<<<dim3(24, 32), 256, 0, stream>>>(xb, wqb, wkb, wvb, bq, bk, bv,
                                                    Qb, Kb, Vtb);
  attn_kernel<<<1024, 256, 0, stream>>>(Qb, Kb, Vtb, Ob);
  oproj_kernel<<<dim3(8, 32), 256, 0, stream>>>(Ob, wob, bo, x, (float*)d_out);
  ln_kernel<<<4096, 256, 0, stream>>>((float*)d_out, gamma, beta);
}

// Round 4
// 114.506 us; speedup vs baseline: 1.8075x; 1.1496x over previous
//
#include <hip/hip_runtime.h>
#include <hip/hip_bf16.h>
#include <cstdint>
#include <cstddef>

// Problem dims
#define NB 2
#define NL 2048
#define NE 1024
#define NH 16
#define ND 64
#define NM (NB * NL)  // 4096 rows total

typedef float f32x4 __attribute__((ext_vector_type(4)));
typedef __bf16 bf16x8 __attribute__((ext_vector_type(8)));
typedef __bf16 bf16x4 __attribute__((ext_vector_type(4)));

#define DEV static __device__ __forceinline__

DEV f32x4 mfma16(bf16x8 a, bf16x8 b, f32x4 c) {
  return __builtin_amdgcn_mfma_f32_16x16x32_bf16(a, b, c, 0, 0, 0);
}

DEV ushort f2bf(float f) {
  uint32_t u = __float_as_uint(f);
  uint32_t r = (u + 0x7fffu + ((u >> 16) & 1u)) >> 16;
  return (ushort)r;
}

#if __has_builtin(__builtin_amdgcn_exp2f)
DEV float fast_exp2(float x) { return __builtin_amdgcn_exp2f(x); }
#else
DEV float fast_exp2(float x) { return exp2f(x); }
#endif

DEV void gl_lds16(const void* src, void* lds_dst) {
  __builtin_amdgcn_global_load_lds(
      (const __attribute__((address_space(1))) void*)src,
      (__attribute__((address_space(3))) void*)lds_dst, 16, 0, 0);
}

// Stage a tile whose rows are 128 bytes (64 bf16) into LDS, linear dest,
// source pre-swizzled with the involution byte ^= ((row&7)<<4) so that
// swizzled ds_read_b128 fragment reads are bank-conflict-reduced.
template <int NCALLS>
DEV void stage_swz(const char* gbase, size_t row_stride_b, char* lds_base, int tid) {
#pragma unroll
  for (int c = 0; c < NCALLS; ++c) {
    uint32_t P = (uint32_t)(c * 4096 + tid * 16);
    uint32_t r = P >> 7;
    uint32_t Lo = P ^ ((r & 7u) << 4);
    gl_lds16(gbase + (size_t)r * row_stride_b + (Lo & 127u), lds_base + P);
  }
}

// ---------------------------------------------------------------- pack
__global__ __launch_bounds__(256) void pack_kernel(
    const float* __restrict__ x, const float* __restrict__ wq,
    const float* __restrict__ wk, const float* __restrict__ wv,
    const float* __restrict__ wo, ushort* __restrict__ xb,
    ushort* __restrict__ wqb, ushort* __restrict__ wkb,
    ushort* __restrict__ wvb, ushort* __restrict__ wob) {
  int64_t q = (int64_t)blockIdx.x * 256 + threadIdx.x;  // quad id, 2097152 total
  const float* src;
  ushort* dst;
  bool cl;
  if (q < 1048576) {
    src = x + q * 4;
    dst = xb + q * 4;
    cl = true;
  } else {
    int64_t r = q - 1048576;
    int wsel = (int)(r >> 18);
    int64_t o = (r & 262143) * 4;
    cl = false;
    if (wsel == 0) { src = wq + o; dst = wqb + o; }
    else if (wsel == 1) { src = wk + o; dst = wkb + o; }
    else if (wsel == 2) { src = wv + o; dst = wvb + o; }
    else { src = wo + o; dst = wob + o; }
  }
  float4 v = *(const float4*)src;
  if (cl) {
    v.x = (v.x != v.x) ? 0.f : fminf(fmaxf(v.x, -1e9f), 1e9f);
    v.y = (v.y != v.y) ? 0.f : fminf(fmaxf(v.y, -1e9f), 1e9f);
    v.z = (v.z != v.z) ? 0.f : fminf(fmaxf(v.z, -1e9f), 1e9f);
    v.w = (v.w != v.w) ? 0.f : fminf(fmaxf(v.w, -1e9f), 1e9f);
  }
  ushort4 o4;
  o4.x = f2bf(v.x);
  o4.y = f2bf(v.y);
  o4.z = f2bf(v.z);
  o4.w = f2bf(v.w);
  *(ushort4*)dst = o4;
}

// ---------------------------------------------------------------- QKV GEMM
// C(4096 x 3072) = xb(4096x1024) @ W^T. Double-buffered LDS, counted vmcnt
// (prefetch stays in flight across barriers). Scattered epilogue:
//  Q (pre-scaled by 0.125*log2e) -> (B,H,L,D) ; K -> (B,H,L,D) ; V -> (B,H,D,L)
__global__ __launch_bounds__(256) void qkv_gemm_kernel(
    const ushort* __restrict__ xb, const ushort* __restrict__ wqb,
    const ushort* __restrict__ wkb, const ushort* __restrict__ wvb,
    const float* __restrict__ bq, const float* __restrict__ bk,
    const float* __restrict__ bv, ushort* __restrict__ Qo,
    ushort* __restrict__ Ko, ushort* __restrict__ Vto) {
  __shared__ __align__(128) char lds[65536];  // A dbuf 2x16K | B dbuf 2x16K
  const int tid = threadIdx.x;
  const int w = tid >> 6, ln = tid & 63;
  const int ln15 = ln & 15, g = ln >> 4;
  const int wm = w >> 1, wn = w & 1;
  const int m0 = blockIdx.y * 128;
  const int which = blockIdx.x >> 3;          // 0=Q 1=K 2=V
  const int n0w = (blockIdx.x & 7) * 128;     // within [0,1024)
  const ushort* Wb = (which == 0) ? wqb : (which == 1) ? wkb : wvb;

  const char* Abase = (const char*)xb + (size_t)m0 * 2048;
  const char* Bbase = (const char*)Wb + (size_t)n0w * 2048;

  f32x4 acc[4][4];
#pragma unroll
  for (int m = 0; m < 4; ++m)
#pragma unroll
    for (int n = 0; n < 4; ++n) acc[m][n] = {0.f, 0.f, 0.f, 0.f};

  int cur = 0;
  stage_swz<4>(Abase, 2048, lds, tid);
  stage_swz<4>(Bbase, 2048, lds + 32768, tid);

  for (int kt = 0; kt < 16; ++kt) {
    if (kt + 1 < 16) {  // prefetch next K-tile; keep in flight across barrier
      stage_swz<4>(Abase + (kt + 1) * 128, 2048, lds + (cur ^ 1) * 16384, tid);
      stage_swz<4>(Bbase + (kt + 1) * 128, 2048,
                   lds + 32768 + (cur ^ 1) * 16384, tid);
      asm volatile("s_waitcnt vmcnt(8)" ::: "memory");  // tile kt landed
    } else {
      asm volatile("s_waitcnt vmcnt(0)" ::: "memory");
    }
    __builtin_amdgcn_s_barrier();
    asm volatile("" ::: "memory");
    const char* ab = lds + cur * 16384;
    const char* bb = lds + 32768 + cur * 16384;
    __builtin_amdgcn_s_setprio(1);
#pragma unroll
    for (int kc = 0; kc < 2; ++kc) {
      bf16x8 af[4], bfr[4];
#pragma unroll
      for (int i = 0; i < 4; ++i) {
        uint32_t ar = (uint32_t)(wm * 64 + i * 16 + ln15);
        uint32_t ao = (ar * 128u + (uint32_t)(kc * 64 + g * 16)) ^ ((ar & 7u) << 4);
        af[i] = *(const bf16x8*)(ab + ao);
        uint32_t br = (uint32_t)(wn * 64 + i * 16 + ln15);
        uint32_t bo_ = (br * 128u + (uint32_t)(kc * 64 + g * 16)) ^ ((br & 7u) << 4);
        bfr[i] = *(const bf16x8*)(bb + bo_);
      }
#pragma unroll
      for (int m = 0; m < 4; ++m)
#pragma unroll
        for (int n = 0; n < 4; ++n) acc[m][n] = mfma16(af[m], bfr[n], acc[m][n]);
    }
    __builtin_amdgcn_s_setprio(0);
    asm volatile("s_waitcnt lgkmcnt(0)" ::: "memory");
    __builtin_amdgcn_s_barrier();
    asm volatile("" ::: "memory");
    cur ^= 1;
  }

  const float* bias = (which == 0) ? bq : (which == 1) ? bk : bv;
  // Q pre-scale: scores use exp2, so fold (1/8)*log2(e) into Q (incl. bias).
  const float sc = (which == 0) ? 0.18033688011112042f : 1.0f;
#pragma unroll
  for (int n = 0; n < 4; ++n) {
    const int col = n0w + wn * 64 + n * 16 + ln15;  // [0,1024)
    const int h = col >> 6, d = col & 63;
    const float bc = bias[col];
#pragma unroll
    for (int m = 0; m < 4; ++m) {
      if (which < 2) {
        ushort* dst = (which == 0) ? Qo : Ko;
#pragma unroll
        for (int j = 0; j < 4; ++j) {
          int mg = m0 + wm * 64 + m * 16 + g * 4 + j;
          int b = mg >> 11, l = mg & 2047;
          dst[((size_t)(b * NH + h) * NL + l) * ND + d] = f2bf((acc[m][n][j] + bc) * sc);
        }
      } else {
        int mg0 = m0 + wm * 64 + m * 16 + g * 4;
        int b = mg0 >> 11, l0 = mg0 & 2047;
        ushort4 pk;
        pk.x = f2bf(acc[m][n][0] + bc);
        pk.y = f2bf(acc[m][n][1] + bc);
        pk.z = f2bf(acc[m][n][2] + bc);
        pk.w = f2bf(acc[m][n][3] + bc);
        *(ushort4*)(Vto + ((size_t)(b * NH + h) * ND + d) * NL + l0) = pk;
      }
    }
  }
}

// ---------------------------------------------------------------- attention
// Causal flash attention. 1024 blocks, one (b,h, 64-row q-tile) each; 4 waves
// x 16 q-rows. Swapped QK^T (S^T in regs -> in-lane softmax). K/V double-
// buffered in LDS; counted vmcnt keeps prefetch in flight across barriers.
// Block mapping: co-resident sets {bx,bx+256,bx+512,bx+768} sum to 66 steps.
__global__ __launch_bounds__(256) void attn_kernel(
    const ushort* __restrict__ Q, const ushort* __restrict__ K,
    const ushort* __restrict__ Vt, ushort* __restrict__ Op) {
  __shared__ __align__(128) char lds[40960];  // K dbuf 16K | V dbuf 16K | P 4x2K
  const int tid = threadIdx.x;
  const int w = tid >> 6, ln = tid & 63;
  const int ln15 = ln & 15, g = ln >> 4;
  const int bx = blockIdx.x;  // [0,1024)
  const int kk = (bx >> 5) & 7, bsel = bx >> 8, bh = bx & 31;
  const int qt = (bsel == 0) ? 31 - kk : (bsel == 1) ? kk
               : (bsel == 2) ? 23 - kk : 8 + kk;
  const int b = bh >> 4, h = bh & 15;
  const ushort* Qh = Q + (size_t)bh * NL * ND;
  const ushort* Kh = K + (size_t)bh * NL * ND;
  const ushort* Vth = Vt + (size_t)bh * ND * NL;
  const uint32_t pbase = 32768u + (uint32_t)w * 2048u;

  const int qb = qt * 64;
  const int r0 = qb + w * 16;  // this wave's first q row
  const int nt = qt + 1;       // KV tiles of 64

  bf16x8 qf[2];
#pragma unroll
  for (int kc = 0; kc < 2; ++kc)
    qf[kc] = *(const bf16x8*)(Qh + (size_t)(r0 + ln15) * ND + kc * 32 + g * 8);

  f32x4 o_acc[4];
#pragma unroll
  for (int n = 0; n < 4; ++n) o_acc[n] = {0.f, 0.f, 0.f, 0.f};
  float m_run = -1e30f, l_run = 0.f;  // per-lane: stats of q-row r0+ln15

  int cur = 0;
  stage_swz<2>((const char*)Kh, 128, lds, tid);
  stage_swz<2>((const char*)Vth, (size_t)NL * 2, lds + 16384, tid);

  for (int t = 0; t < nt; ++t) {
    const int s0 = t * 64;
    if (t + 1 < nt) {  // prefetch next K/V tile; keep in flight across barrier
      stage_swz<2>((const char*)Kh + (size_t)(s0 + 64) * 128, 128,
                   lds + (cur ^ 1) * 8192, tid);
      stage_swz<2>((const char*)Vth + (size_t)(s0 + 64) * 2, (size_t)NL * 2,
                   lds + 16384 + (cur ^ 1) * 8192, tid);
      asm volatile("s_waitcnt vmcnt(4)" ::: "memory");  // tile t landed; 4 stay
    } else {
      asm volatile("s_waitcnt vmcnt(0)" ::: "memory");
    }
    __builtin_amdgcn_s_barrier();
    asm volatile("" ::: "memory");

    const char* kb = lds + cur * 8192;
    const char* vb = lds + 16384 + cur * 8192;

    // S^T = K Q^T : s_acc[n][j] holds k = s0+n*16+g*4+j, q = r0+ln15
    f32x4 s_acc[4];
#pragma unroll
    for (int n = 0; n < 4; ++n) s_acc[n] = {0.f, 0.f, 0.f, 0.f};
    __builtin_amdgcn_s_setprio(1);
#pragma unroll
    for (int kc = 0; kc < 2; ++kc) {
      bf16x8 kf[4];
#pragma unroll
      for (int n = 0; n < 4; ++n) {
        uint32_t kr = (uint32_t)(n * 16 + ln15);
        uint32_t off = (kr * 128u + (uint32_t)(kc * 64 + g * 16)) ^ ((kr & 7u) << 4);
        kf[n] = *(const bf16x8*)(kb + off);
      }
#pragma unroll
      for (int n = 0; n < 4; ++n) s_acc[n] = mfma16(kf[n], qf[kc], s_acc[n]);
    }
    __builtin_amdgcn_s_setprio(0);

    // causal mask only on the (last, block-uniform) diagonal tile
    if (t == nt - 1) {
      const int qi = r0 + ln15;
#pragma unroll
      for (int n = 0; n < 4; ++n)
#pragma unroll
        for (int j = 0; j < 4; ++j) {
          int si = s0 + n * 16 + g * 4 + j;
          s_acc[n][j] = (si > qi) ? -1e30f : s_acc[n][j];
        }
    }

    // online softmax, fully in-lane over 16 k-values + 2-step cross-g reduce
    float mx = s_acc[0][0];
#pragma unroll
    for (int n = 0; n < 4; ++n)
#pragma unroll
      for (int j = 0; j < 4; ++j) mx = fmaxf(mx, s_acc[n][j]);
    mx = fmaxf(mx, __shfl_xor(mx, 16));
    mx = fmaxf(mx, __shfl_xor(mx, 32));
    if (__any(mx > m_run + 8.0f)) {  // defer-max: P bounded by 2^8
      float mn = fmaxf(m_run, mx);
      float al = fast_exp2(m_run - mn);
      m_run = mn;
      l_run *= al;
#pragma unroll
      for (int j = 0; j < 4; ++j) {
        float aj = __shfl(al, g * 4 + j);  // alpha of q-row g*4+j
#pragma unroll
        for (int n = 0; n < 4; ++n) o_acc[n][j] *= aj;
      }
    }
    float ps = 0.f;
#pragma unroll
    for (int n = 0; n < 4; ++n) {
      float p0 = fast_exp2(s_acc[n][0] - m_run);
      float p1 = fast_exp2(s_acc[n][1] - m_run);
      float p2 = fast_exp2(s_acc[n][2] - m_run);
      float p3 = fast_exp2(s_acc[n][3] - m_run);
      ps += (p0 + p1) + (p2 + p3);
      bf16x4 pk = {(__bf16)p0, (__bf16)p1, (__bf16)p2, (__bf16)p3};
      // P[q=ln15][k=n*16+g*4 .. +3], row-swizzled like K/V
      uint32_t off = ((uint32_t)ln15 * 128u + (uint32_t)(n * 32 + g * 8)) ^
                     (((uint32_t)ln15 & 7u) << 4);
      *(bf16x4*)(lds + pbase + off) = pk;
    }
    ps += __shfl_xor(ps, 16);
    ps += __shfl_xor(ps, 32);
    l_run += ps;

    // O += P V  (P wave-private)
    __builtin_amdgcn_s_setprio(1);
#pragma unroll
    for (int kc = 0; kc < 2; ++kc) {
      uint32_t poff = ((uint32_t)ln15 * 128u + (uint32_t)(kc * 64 + g * 16)) ^
                      (((uint32_t)ln15 & 7u) << 4);
      bf16x8 pf = *(const bf16x8*)(lds + pbase + poff);
      bf16x8 vf[4];
#pragma unroll
      for (int n = 0; n < 4; ++n) {
        uint32_t vr = (uint32_t)(n * 16 + ln15);
        uint32_t off = (vr * 128u + (uint32_t)(kc * 64 + g * 16)) ^ ((vr & 7u) << 4);
        vf[n] = *(const bf16x8*)(vb + off);
      }
#pragma unroll
      for (int n = 0; n < 4; ++n) o_acc[n] = mfma16(pf, vf[n], o_acc[n]);
    }
    __builtin_amdgcn_s_setprio(0);

    // my LDS reads delivered; then all waves synced before next overwrite
    asm volatile("s_waitcnt lgkmcnt(0)" ::: "memory");
    __builtin_amdgcn_s_barrier();
    asm volatile("" ::: "memory");
    cur ^= 1;
  }

  // write O (bf16) packed as (B*L, E). o_acc[n][j]: q=r0+g*4+j, d=n*16+ln15
  float invl = 1.0f / l_run;
#pragma unroll
  for (int j = 0; j < 4; ++j) {
    float inv = __shfl(invl, g * 4 + j);
    int qi = r0 + g * 4 + j;
    size_t rowo = ((size_t)b * NL + qi) * NE + h * ND;
#pragma unroll
    for (int n = 0; n < 4; ++n) Op[rowo + n * 16 + ln15] = f2bf(o_acc[n][j] * inv);
  }
}

// ---------------------------------------------------------------- out-proj + residual
// Double-buffered LDS, counted vmcnt (same structure as qkv_gemm).
__global__ __launch_bounds__(256) void oproj_kernel(
    const ushort* __restrict__ ob, const ushort* __restrict__ wob,
    const float* __restrict__ bo, const float* __restrict__ x,
    float* __restrict__ out) {
  __shared__ __align__(128) char lds[65536];  // A dbuf 2x16K | B dbuf 2x16K
  const int tid = threadIdx.x;
  const int w = tid >> 6, ln = tid & 63;
  const int ln15 = ln & 15, g = ln >> 4;
  const int wm = w >> 1, wn = w & 1;
  const int m0 = blockIdx.y * 128;
  const int n0 = blockIdx.x * 128;

  const char* Abase = (const char*)ob + (size_t)m0 * 2048;
  const char* Bbase = (const char*)wob + (size_t)n0 * 2048;

  f32x4 acc[4][4];
#pragma unroll
  for (int m = 0; m < 4; ++m)
#pragma unroll
    for (int n = 0; n < 4; ++n) acc[m][n] = {0.f, 0.f, 0.f, 0.f};

  int cur = 0;
  stage_swz<4>(Abase, 2048, lds, tid);
  stage_swz<4>(Bbase, 2048, lds + 32768, tid);

  for (int kt = 0; kt < 16; ++kt) {
    if (kt + 1 < 16) {
      stage_swz<4>(Abase + (kt + 1) * 128, 2048, lds + (cur ^ 1) * 16384, tid);
      stage_swz<4>(Bbase + (kt + 1) * 128, 2048,
                   lds + 32768 + (cur ^ 1) * 16384, tid);
      asm volatile("s_waitcnt vmcnt(8)" ::: "memory");
    } else {
      asm volatile("s_waitcnt vmcnt(0)" ::: "memory");
    }
    __builtin_amdgcn_s_barrier();
    asm volatile("" ::: "memory");
    const char* ab = lds + cur * 16384;
    const char* bb = lds + 32768 + cur * 16384;
    __builtin_amdgcn_s_setprio(1);
#pragma unroll
    for (int kc = 0; kc < 2; ++kc) {
      bf16x8 af[4], bfr[4];
#pragma unroll
      for (int i = 0; i < 4; ++i) {
        uint32_t ar = (uint32_t)(wm * 64 + i * 16 + ln15);
        uint32_t ao = (ar * 128u + (uint32_t)(kc * 64 + g * 16)) ^ ((ar & 7u) << 4);
        af[i] = *(const bf16x8*)(ab + ao);
        uint32_t br = (uint32_t)(wn * 64 + i * 16 + ln15);
        uint32_t bo_ = (br * 128u + (uint32_t)(kc * 64 + g * 16)) ^ ((br & 7u) << 4);
        bfr[i] = *(const bf16x8*)(bb + bo_);
      }
#pragma unroll
      for (int m = 0; m < 4; ++m)
#pragma unroll
        for (int n = 0; n < 4; ++n) acc[m][n] = mfma16(af[m], bfr[n], acc[m][n]);
    }
    __builtin_amdgcn_s_setprio(0);
    asm volatile("s_waitcnt lgkmcnt(0)" ::: "memory");
    __builtin_amdgcn_s_barrier();
    asm volatile("" ::: "memory");
    cur ^= 1;
  }

#pragma unroll
  for (int n = 0; n < 4; ++n) {
    const int col = n0 + wn * 64 + n * 16 + ln15;
    const float bc = bo[col];
#pragma unroll
    for (int m = 0; m < 4; ++m)
#pragma unroll
      for (int j = 0; j < 4; ++j) {
        int mg = m0 + wm * 64 + m * 16 + g * 4 + j;
        size_t idx = (size_t)mg * NE + col;
        out[idx] = acc[m][n][j] + bc + x[idx];
      }
  }
}

// ---------------------------------------------------------------- LayerNorm (in-place)
__global__ __launch_bounds__(256) void ln_kernel(float* __restrict__ io,
                                                 const float* __restrict__ gamma,
                                                 const float* __restrict__ beta) {
  const int row = blockIdx.x, tid = threadIdx.x;
  const int w = tid >> 6, ln = tid & 63;
  float4 v = *(const float4*)(io + (size_t)row * NE + tid * 4);
  float s = v.x + v.y + v.z + v.w;
  float ss = v.x * v.x + v.y * v.y + v.z * v.z + v.w * v.w;
#pragma unroll
  for (int d = 1; d < 64; d <<= 1) {
    s += __shfl_xor(s, d);
    ss += __shfl_xor(ss, d);
  }
  __shared__ float red[8];
  if (ln == 0) {
    red[w] = s;
    red[4 + w] = ss;
  }
  __syncthreads();
  s = red[0] + red[1] + red[2] + red[3];
  ss = red[4] + red[5] + red[6] + red[7];
  const float mu = s * (1.0f / (float)NE);
  float var = ss * (1.0f / (float)NE) - mu * mu;
  const float inv = rsqrtf(var + 1e-5f);
  float4 gv = *(const float4*)(gamma + tid * 4);
  float4 bv = *(const float4*)(beta + tid * 4);
  float4 o;
  o.x = (v.x - mu) * inv * gv.x + bv.x;
  o.y = (v.y - mu) * inv * gv.y + bv.y;
  o.z = (v.z - mu) * inv * gv.z + bv.z;
  o.w = (v.w - mu) * inv * gv.w + bv.w;
  *(float4*)(io + (size_t)row * NE + tid * 4) = o;
}

// ---------------------------------------------------------------- launch
extern "C" void kernel_launch(void* const* d_in, const int* in_sizes, int n_in,
                              void* d_out, int out_size, void* d_ws, size_t ws_size,
                              hipStream_t stream) {
  const float* x = (const float*)d_in[0];
  // d_in[1] = mask (causal, recomputed analytically -> unused)
  const float* Wq = (const float*)d_in[2];
  const float* bq = (const float*)d_in[3];
  const float* Wk = (const float*)d_in[4];
  const float* bk = (const float*)d_in[5];
  const float* Wv = (const float*)d_in[6];
  const float* bv = (const float*)d_in[7];
  const float* Wo = (const float*)d_in[8];
  const float* bo = (const float*)d_in[9];
  const float* gamma = (const float*)d_in[10];
  const float* beta = (const float*)d_in[11];

  char* ws = (char*)d_ws;
  ushort* xb  = (ushort*)(ws + 0);          // 8 MB  (4096x1024 bf16)
  ushort* wqb = (ushort*)(ws + 8388608);    // 2 MB
  ushort* wkb = (ushort*)(ws + 10485760);   // 2 MB
  ushort* wvb = (ushort*)(ws + 12582912);   // 2 MB
  ushort* wob = (ushort*)(ws + 14680064);   // 2 MB
  ushort* Qb  = (ushort*)(ws + 16777216);   // 8 MB (B,H,L,D) pre-scaled
  ushort* Kb  = (ushort*)(ws + 25165824);   // 8 MB (B,H,L,D)
  ushort* Vtb = (ushort*)(ws + 33554432);   // 8 MB (B,H,D,L)
  ushort* Ob  = (ushort*)(ws + 41943040);   // 8 MB (B*L, E)

  pack_kernel<<<8192, 256, 0, stream>>>(x, Wq, Wk, Wv, Wo, xb, wqb, wkb, wvb, wob);
  qkv_gemm_kernel<<<dim3(24, 32), 256, 0, stream>>>(xb, wqb, wkb, wvb, bq, bk, bv,
                                                    Qb, Kb, Vtb);
  attn_kernel<<<1024, 256, 0, stream>>>(Qb, Kb, Vtb, Ob);
  oproj_kernel<<<dim3(8, 32), 256, 0, stream>>>(Ob, wob, bo, x, (float*)d_out);
  ln_kernel<<<4096, 256, 0, stream>>>((float*)d_out, gamma, beta);
}